// Round 5
// baseline (124.073 us; speedup 1.0000x reference)
//
#include <hip/hip_runtime.h>
#include <math.h>

// ---------------------------------------------------------------------------
// HybridQuantumDQN: encoder MLP -> 8-qubit statevector sim -> decoder MLP.
// Round 5: R4's packed-fp32 (v_pk_fma_f32) gates, but NO LDS transposes:
//  - Layout fixed (A): 4 samples/wave64, 16 lanes/sample, amp = L*16 + t
//    (L = lane&15 -> amp bits 7..4, t = reg idx -> amp bits 3..0).
//  - Wires 4..7: in-lane SU(2) pair update, 8 pk per pair.
//  - Wires 0..3: cross-lane SU(2): partner via DPP (xor 8/2/1) or ds_swizzle
//    (xor 4), per-lane sign masks fold the hi/lo row selection into the
//    coefficients, 4 pk + 2 exchange per amp.
//  - LDS = 512 B (Rot coeffs only) -> occupancy cap lifted (R4's 18.9 KB
//    transpose buffer capped CU residency at ~2 waves/SIMD).
// ---------------------------------------------------------------------------

#define PI_F 3.14159265358979323846f

typedef float v2f __attribute__((ext_vector_type(2)));

struct C2 { float re, im; };
__device__ __forceinline__ C2 cmul(C2 a, C2 b) {
    C2 r;
    r.re = fmaf(a.re, b.re, -a.im * b.im);
    r.im = fmaf(a.re, b.im,  a.im * b.re);
    return r;
}
__device__ __forceinline__ float fxor(float x, int m) {
    return __int_as_float(__float_as_int(x) ^ m);
}

// ---------------- packed fp32 primitives (VOP3P) ----------------
__device__ __forceinline__ v2f pk_mul(v2f a, v2f b) {
    v2f d; asm("v_pk_mul_f32 %0, %1, %2" : "=v"(d) : "v"(a), "v"(b)); return d;
}
__device__ __forceinline__ v2f pk_mul_neg(v2f a, v2f b) {
    v2f d; asm("v_pk_mul_f32 %0, %1, %2 neg_lo:[1,0] neg_hi:[1,0]"
               : "=v"(d) : "v"(a), "v"(b)); return d;
}
__device__ __forceinline__ v2f pk_fma(v2f a, v2f b, v2f c) {
    v2f d; asm("v_pk_fma_f32 %0, %1, %2, %3" : "=v"(d) : "v"(a), "v"(b), "v"(c)); return d;
}
// d = -(a*b) + c
__device__ __forceinline__ v2f pk_fma_nn(v2f a, v2f b, v2f c) {
    v2f d; asm("v_pk_fma_f32 %0, %1, %2, %3 neg_lo:[1,0,0] neg_hi:[1,0,0]"
               : "=v"(d) : "v"(a), "v"(b), "v"(c)); return d;
}
// d.lo = -a.lo*b.hi + c.lo ; d.hi = a.hi*b.lo + c.hi   (complex cross term)
__device__ __forceinline__ v2f pk_fma_swl(v2f a, v2f b, v2f c) {
    v2f d; asm("v_pk_fma_f32 %0, %1, %2, %3 op_sel:[0,1,0] op_sel_hi:[1,0,1] neg_lo:[1,0,0]"
               : "=v"(d) : "v"(a), "v"(b), "v"(c)); return d;
}
// d.lo = a.lo*b.hi + c.lo ; d.hi = -a.hi*b.lo + c.hi
__device__ __forceinline__ v2f pk_fma_swh(v2f a, v2f b, v2f c) {
    v2f d; asm("v_pk_fma_f32 %0, %1, %2, %3 op_sel:[0,1,0] op_sel_hi:[1,0,1] neg_hi:[1,0,0]"
               : "=v"(d) : "v"(a), "v"(b), "v"(c)); return d;
}

// ---------------- cross-lane exchange ----------------
template<int CTRL>
__device__ __forceinline__ float dppf(float x) {
    int xi = __float_as_int(x);
    int r = __builtin_amdgcn_update_dpp(xi, xi, CTRL, 0xF, 0xF, false);
    return __int_as_float(r);
}
template<int M>
__device__ __forceinline__ float lxor(float x) {
    if constexpr (M == 1)      return dppf<0xB1>(x);   // quad_perm [1,0,3,2]
    else if constexpr (M == 2) return dppf<0x4E>(x);   // quad_perm [2,3,0,1]
    else if constexpr (M == 4) return __int_as_float(
        __builtin_amdgcn_ds_swizzle(__float_as_int(x), 0x101F));  // lane^4
    else                       return dppf<0x128>(x);  // row_ror:8 == lane^8
}

// ---------------- gates ----------------
// fused SU(2) gate G = Rot * RY: columns (a,b); G = [[a,-conj(b)],[b,conj(a)]]
__device__ __forceinline__ void load_G2(const float* __restrict__ c_lds, int g,
                                        float cc, float ss,
                                        float& ar, float& ai, float& br, float& bi) {
    const float4 c0 = *(const float4*)(c_lds + 4 * g);  // aR.re aR.im bR.re bR.im
    ar = fmaf(c0.x, cc, -c0.z * ss);
    ai = fmaf(c0.y, cc,  c0.w * ss);
    br = fmaf(c0.z, cc,  c0.x * ss);
    bi = fmaf(c0.w, cc, -c0.y * ss);
}

// cross-lane SU(2): new = cS*z + cO*p, coefficients pre-sign-adjusted per lane
// (lo lane: cS=(ar,ai), cO=(-br,bi); hi lane: cS=(ar,-ai), cO=(br,bi))
template<int M>
__device__ __forceinline__ void su2_cross(v2f cSr, v2f cSi, v2f cOr, v2f cOi,
                                          v2f z[16]) {
#pragma unroll
    for (int t = 0; t < 16; t++) {
        v2f p;
        p.x = lxor<M>(z[t].x);
        p.y = lxor<M>(z[t].y);
        v2f n = pk_mul(cSr, z[t]);
        n = pk_fma_swl(cSi, z[t], n);
        n = pk_fma   (cOr, p, n);
        n = pk_fma_swl(cOi, p, n);
        z[t] = n;
    }
}

// in-lane SU(2) on register-index bit ST: 8 pk per pair
template<int ST>
__device__ __forceinline__ void su2_inlane(v2f arr, v2f aii, v2f brr, v2f bii,
                                           v2f z[16]) {
#pragma unroll
    for (int t = 0; t < 16; t++) {
        if ((t & ST) == 0) {
            const int u = t + ST;
            v2f x = z[t], y = z[u];
            v2f nx = pk_mul(arr, x);
            nx = pk_fma_swl(aii, x, nx);
            nx = pk_fma_nn (brr, y, nx);
            nx = pk_fma_swl(bii, y, nx);
            v2f ny = pk_mul(brr, x);
            ny = pk_fma_swl(bii, x, ny);
            ny = pk_fma   (arr, y, ny);
            ny = pk_fma_swh(aii, y, ny);
            z[t] = nx; z[u] = ny;
        }
    }
}

// final RY: cross (cO pre-signed per lane), 2 pk + 2 exch per amp
template<int M>
__device__ __forceinline__ void ry_cross(v2f cc, v2f cO, v2f z[16]) {
#pragma unroll
    for (int t = 0; t < 16; t++) {
        v2f p;
        p.x = lxor<M>(z[t].x);
        p.y = lxor<M>(z[t].y);
        z[t] = pk_fma(cO, p, pk_mul(cc, z[t]));
    }
}
template<int ST>
__device__ __forceinline__ void ry_inlane(v2f cc, v2f ss, v2f z[16]) {
#pragma unroll
    for (int t = 0; t < 16; t++) {
        if ((t & ST) == 0) {
            const int u = t + ST;
            v2f x = z[t], y = z[u];
            z[t] = pk_fma_nn(ss, y, pk_mul(cc, x));   // c*x - s*y
            z[u] = pk_fma   (cc, y, pk_mul(ss, x));   // s*x + c*y
        }
    }
}

__device__ __constant__ const bool CZNEG[16] =
    { false,false,false,true,  false,false,true,false,
      false,false,false,true,  true, true, false,true };

__global__ __launch_bounds__(256) void qdqn_kernel(
    const float* __restrict__ x,
    const float* __restrict__ ew1, const float* __restrict__ eb1,
    const float* __restrict__ ew2, const float* __restrict__ eb2,
    const float* __restrict__ qw,
    const float* __restrict__ dw1, const float* __restrict__ db1,
    const float* __restrict__ dw2, const float* __restrict__ db2,
    float* __restrict__ out, int B, int NL) {
    __shared__ __align__(16) float c_lds[32 * 4];

    const int tid = threadIdx.x;
    const int n_gates = NL * 8;

    // ---- Rot SU(2) coeffs once per block: a = e^{-iA}c, b = e^{-iB}s ----
    if (tid < n_gates) {
        const int g = tid;
        float phi = qw[3 * g + 0], th = qw[3 * g + 1], om = qw[3 * g + 2];
        float c = __cosf(0.5f * th), s = __sinf(0.5f * th);
        float A = 0.5f * (phi + om), Bb = 0.5f * (phi - om);
        float* o = c_lds + 4 * g;
        o[0] =  __cosf(A) * c;  o[1] = -__sinf(A) * c;
        o[2] =  __cosf(Bb) * s; o[3] = -__sinf(Bb) * s;
    }
    __syncthreads();

    const int lane = tid & 63;
    const int L = lane & 15;
    int s = blockIdx.x * 16 + (tid >> 4);   // 16 samples per 256-thr block
    if (s >= B) s = B - 1;

    // ---------------- encoder MLP ----------------
    float xv[16];
    const float4* xp = (const float4*)(x + s * 16);
#pragma unroll
    for (int i = 0; i < 4; i++) {
        float4 v = xp[i];
        xv[4*i] = v.x; xv[4*i+1] = v.y; xv[4*i+2] = v.z; xv[4*i+3] = v.w;
    }
    float hbuf[8];
#pragma unroll
    for (int j = 0; j < 8; j++) {
        float a = eb1[j];
#pragma unroll
        for (int i = 0; i < 16; i++) a = fmaf(ew1[j * 16 + i], xv[i], a);
        hbuf[j] = fmaxf(a, 0.0f);
    }
    float cq[8], sq[8];
#pragma unroll
    for (int q = 0; q < 8; q++) {
        float a = eb2[q];
#pragma unroll
        for (int j = 0; j < 8; j++) a = fmaf(ew2[q * 8 + j], hbuf[j], a);
        float e = 1.0f - __fdividef(2.0f, __expf(2.0f * a) + 1.0f);  // tanh
        float ang = e * (0.5f * PI_F);
        cq[q] = __cosf(ang);
        sq[q] = __sinf(ang);
    }

    // ---- per-lane sign masks for cross wires q=0..3 (bit 3-q of L) ----
    int hiM[4], loM[4];
#pragma unroll
    for (int q = 0; q < 4; q++) {
        int hi = (L >> (3 - q)) & 1;
        hiM[q] = hi << 31;                 // flips ai when hi lane
        loM[q] = hiM[q] ^ 0x80000000;      // flips br when lo lane
    }

    // ---- CZ lane scalars (layout A: hi nibble = L, lo nibble = t) ----
    const int L0 = L & 1, L1b = (L >> 1) & 1, L2b = (L >> 2) & 1, L3b = (L >> 3) & 1;
    const int cnt = (L3b & L2b) + (L2b & L1b) + (L1b & L0);
    const float mL = (cnt & 1) ? -1.0f : 1.0f;
    const float mH = L0 ? -mL : mL;
    const v2f mL2 = (v2f){mL, mL}, mH2 = (v2f){mH, mH};

    // ---------------- layer 0: product state, CZ folded --------------------
    v2f z[16];
    {
        C2 P; P.re = 1.0f; P.im = 0.0f;
        C2 F[4][2];
#pragma unroll
        for (int q = 0; q < 8; q++) {
            float ar, ai, br, bi;
            load_G2(c_lds, q, cq[q], sq[q], ar, ai, br, bi);
            if (q < 4) {
                const bool hi = (L >> (3 - q)) & 1;
                C2 f; f.re = hi ? br : ar; f.im = hi ? bi : ai;  // column 0
                P = cmul(P, f);
            } else {
                F[q-4][0].re = ar; F[q-4][0].im = ai;
                F[q-4][1].re = br; F[q-4][1].im = bi;
            }
        }
        C2 A0 = cmul(P, F[0][0]), A1 = cmul(P, F[0][1]);
        C2 Bv[4];
        Bv[0] = cmul(A0, F[1][0]); Bv[1] = cmul(A0, F[1][1]);
        Bv[2] = cmul(A1, F[1][0]); Bv[3] = cmul(A1, F[1][1]);
        C2 Cv[8];
#pragma unroll
        for (int i = 0; i < 8; i++) Cv[i] = cmul(Bv[i >> 1], F[2][i & 1]);
#pragma unroll
        for (int t = 0; t < 16; t++) {
            C2 v = cmul(Cv[t >> 1], F[3][t & 1]);
            float m = (t < 8) ? mL : mH;
            m = CZNEG[t] ? -m : m;
            z[t].x = v.re * m;
            z[t].y = v.im * m;
        }
    }

    // ---------------- layers 1..NL-1 ---------------------------------------
    for (int l = 1; l < NL; l++) {
        const int g0 = l * 8;
        float ar, ai, br, bi;
        load_G2(c_lds, g0+0, cq[0], sq[0], ar, ai, br, bi);
        su2_cross<8>((v2f){ar,ar}, (v2f){fxor(ai,hiM[0]),fxor(ai,hiM[0])},
                     (v2f){fxor(br,loM[0]),fxor(br,loM[0])}, (v2f){bi,bi}, z);
        load_G2(c_lds, g0+1, cq[1], sq[1], ar, ai, br, bi);
        su2_cross<4>((v2f){ar,ar}, (v2f){fxor(ai,hiM[1]),fxor(ai,hiM[1])},
                     (v2f){fxor(br,loM[1]),fxor(br,loM[1])}, (v2f){bi,bi}, z);
        load_G2(c_lds, g0+2, cq[2], sq[2], ar, ai, br, bi);
        su2_cross<2>((v2f){ar,ar}, (v2f){fxor(ai,hiM[2]),fxor(ai,hiM[2])},
                     (v2f){fxor(br,loM[2]),fxor(br,loM[2])}, (v2f){bi,bi}, z);
        load_G2(c_lds, g0+3, cq[3], sq[3], ar, ai, br, bi);
        su2_cross<1>((v2f){ar,ar}, (v2f){fxor(ai,hiM[3]),fxor(ai,hiM[3])},
                     (v2f){fxor(br,loM[3]),fxor(br,loM[3])}, (v2f){bi,bi}, z);
        load_G2(c_lds, g0+4, cq[4], sq[4], ar, ai, br, bi);
        su2_inlane<8>((v2f){ar,ar}, (v2f){ai,ai}, (v2f){br,br}, (v2f){bi,bi}, z);
        load_G2(c_lds, g0+5, cq[5], sq[5], ar, ai, br, bi);
        su2_inlane<4>((v2f){ar,ar}, (v2f){ai,ai}, (v2f){br,br}, (v2f){bi,bi}, z);
        load_G2(c_lds, g0+6, cq[6], sq[6], ar, ai, br, bi);
        su2_inlane<2>((v2f){ar,ar}, (v2f){ai,ai}, (v2f){br,br}, (v2f){bi,bi}, z);
        load_G2(c_lds, g0+7, cq[7], sq[7], ar, ai, br, bi);
        su2_inlane<1>((v2f){ar,ar}, (v2f){ai,ai}, (v2f){br,br}, (v2f){bi,bi}, z);
        // CZ diagonal
#pragma unroll
        for (int t = 0; t < 16; t++) {
            v2f m = (t < 8) ? mL2 : mH2;
            z[t] = CZNEG[t] ? pk_mul_neg(m, z[t]) : pk_mul(m, z[t]);
        }
    }

    // ---------------- final RY layer ---------------------------------------
    {
        v2f cc, cO, ss;
        cc=(v2f){cq[0],cq[0]}; cO=(v2f){fxor(sq[0],loM[0]),fxor(sq[0],loM[0])};
        ry_cross<8>(cc, cO, z);
        cc=(v2f){cq[1],cq[1]}; cO=(v2f){fxor(sq[1],loM[1]),fxor(sq[1],loM[1])};
        ry_cross<4>(cc, cO, z);
        cc=(v2f){cq[2],cq[2]}; cO=(v2f){fxor(sq[2],loM[2]),fxor(sq[2],loM[2])};
        ry_cross<2>(cc, cO, z);
        cc=(v2f){cq[3],cq[3]}; cO=(v2f){fxor(sq[3],loM[3]),fxor(sq[3],loM[3])};
        ry_cross<1>(cc, cO, z);
        cc=(v2f){cq[4],cq[4]}; ss=(v2f){sq[4],sq[4]}; ry_inlane<8>(cc, ss, z);
        cc=(v2f){cq[5],cq[5]}; ss=(v2f){sq[5],sq[5]}; ry_inlane<4>(cc, ss, z);
        cc=(v2f){cq[6],cq[6]}; ss=(v2f){sq[6],sq[6]}; ry_inlane<2>(cc, ss, z);
        cc=(v2f){cq[7],cq[7]}; ss=(v2f){sq[7],sq[7]}; ry_inlane<1>(cc, ss, z);
    }

    // ---------------- probs -> <Z_w> ----------------
    float p[16];
#pragma unroll
    for (int t = 0; t < 16; t++) p[t] = fmaf(z[t].x, z[t].x, z[t].y * z[t].y);

    float e0 = p[0]+p[1],  e1 = p[2]+p[3],  e2 = p[4]+p[5],  e3 = p[6]+p[7];
    float e4 = p[8]+p[9],  e5 = p[10]+p[11], e6 = p[12]+p[13], e7 = p[14]+p[15];
    float q0 = e0+e1, q1 = e2+e3, q2 = e4+e5, q3 = e6+e7;
    float h0 = q0+q1, h1 = q2+q3;
    float sumP = h0 + h1;

    float zv[8];
#pragma unroll
    for (int w = 0; w < 4; w++)
        zv[w] = ((L >> (3 - w)) & 1) ? -sumP : sumP;
    zv[4] = h0 - h1;
    zv[5] = (q0 - q1) + (q2 - q3);
    zv[6] = (e0 - e1) + (e2 - e3) + (e4 - e5) + (e6 - e7);
    zv[7] = (p[0]-p[1]) + (p[2]-p[3]) + (p[4]-p[5]) + (p[6]-p[7])
          + (p[8]-p[9]) + (p[10]-p[11]) + (p[12]-p[13]) + (p[14]-p[15]);

#pragma unroll
    for (int w = 0; w < 8; w++) zv[w] += lxor<1>(zv[w]);
#pragma unroll
    for (int w = 0; w < 8; w++) zv[w] += lxor<2>(zv[w]);
#pragma unroll
    for (int w = 0; w < 8; w++) zv[w] += lxor<4>(zv[w]);
#pragma unroll
    for (int w = 0; w < 8; w++) zv[w] += lxor<8>(zv[w]);

    // ---------------- decoder MLP ----------------
    float h2[8];
#pragma unroll
    for (int j = 0; j < 8; j++) {
        float a = db1[j];
#pragma unroll
        for (int w = 0; w < 8; w++) a = fmaf(dw1[j * 8 + w], zv[w], a);
        h2[j] = fmaxf(a, 0.0f);
    }
    if (L < 4) {
        float a = db2[L];
#pragma unroll
        for (int j = 0; j < 8; j++) a = fmaf(dw2[L * 8 + j], h2[j], a);
        out[s * 4 + L] = a;
    }
}

extern "C" void kernel_launch(void* const* d_in, const int* in_sizes, int n_in,
                              void* d_out, int out_size, void* d_ws, size_t ws_size,
                              hipStream_t stream) {
    const float* x   = (const float*)d_in[0];
    const float* ew1 = (const float*)d_in[1];
    const float* eb1 = (const float*)d_in[2];
    const float* ew2 = (const float*)d_in[3];
    const float* eb2 = (const float*)d_in[4];
    const float* qw  = (const float*)d_in[5];
    const float* dw1 = (const float*)d_in[6];
    const float* db1 = (const float*)d_in[7];
    const float* dw2 = (const float*)d_in[8];
    const float* db2 = (const float*)d_in[9];
    float* out = (float*)d_out;

    int B = in_sizes[0] / 16;        // 32768
    int n_gates = in_sizes[5] / 3;   // 32
    int NL = n_gates / 8;            // 4

    // 16 samples per 256-thread block (4 waves x 4 samples/wave)
    int blocks = (B + 15) / 16;
    qdqn_kernel<<<blocks, 256, 0, stream>>>(x, ew1, eb1, ew2, eb2, qw,
                                            dw1, db1, dw2, db2, out, B, NL);
}

// Round 6
// 119.777 us; speedup vs baseline: 1.0359x; 1.0359x over previous
//
#include <hip/hip_runtime.h>
#include <math.h>

// ---------------------------------------------------------------------------
// HybridQuantumDQN: encoder MLP -> 8-qubit statevector sim -> decoder MLP.
// Round 6: 8 samples/wave64; 8 lanes/sample; 32 complex amps/lane (v2f).
//   amp = (G<<5)|t, G = lane&7 (amp bits 7..5), t = reg idx (amp bits 4..0).
//   Wires 0..2 -> lane bits 2..0: cross-lane xor4 (ds_swizzle), xor2/xor1
//   (quad_perm DPP). Wires 3..7 -> t bits 4..0: in-lane pair updates.
// Packed fp32 (v_pk_fma_f32) for all state math. Encoder/decoder/transcen-
// dentals split across the 8 lanes of a sample via wave-local LDS exchange.
// Layer 0 = product state (per-lane scalar P x in-place 5-wire Kronecker).
// CZ chain = closed-form +-1 diagonal (per-lane scalars x compile-time t part).
// ---------------------------------------------------------------------------

#define PI_F 3.14159265358979323846f

typedef float v2f __attribute__((ext_vector_type(2)));

struct C2 { float re, im; };
__device__ __forceinline__ C2 cmul(C2 a, C2 b) {
    C2 r;
    r.re = fmaf(a.re, b.re, -a.im * b.im);
    r.im = fmaf(a.re, b.im,  a.im * b.re);
    return r;
}
__device__ __forceinline__ float fxor(float x, int m) {
    return __int_as_float(__float_as_int(x) ^ m);
}

// ---------------- packed fp32 primitives (VOP3P) ----------------
__device__ __forceinline__ v2f pk_mul(v2f a, v2f b) {
    v2f d; asm("v_pk_mul_f32 %0, %1, %2" : "=v"(d) : "v"(a), "v"(b)); return d;
}
__device__ __forceinline__ v2f pk_mul_neg(v2f a, v2f b) {
    v2f d; asm("v_pk_mul_f32 %0, %1, %2 neg_lo:[1,0] neg_hi:[1,0]"
               : "=v"(d) : "v"(a), "v"(b)); return d;
}
__device__ __forceinline__ v2f pk_fma(v2f a, v2f b, v2f c) {
    v2f d; asm("v_pk_fma_f32 %0, %1, %2, %3" : "=v"(d) : "v"(a), "v"(b), "v"(c)); return d;
}
// d = -(a*b) + c
__device__ __forceinline__ v2f pk_fma_nn(v2f a, v2f b, v2f c) {
    v2f d; asm("v_pk_fma_f32 %0, %1, %2, %3 neg_lo:[1,0,0] neg_hi:[1,0,0]"
               : "=v"(d) : "v"(a), "v"(b), "v"(c)); return d;
}
// d.lo = -a.lo*b.hi + c.lo ; d.hi = a.hi*b.lo + c.hi   (complex cross term)
__device__ __forceinline__ v2f pk_fma_swl(v2f a, v2f b, v2f c) {
    v2f d; asm("v_pk_fma_f32 %0, %1, %2, %3 op_sel:[0,1,0] op_sel_hi:[1,0,1] neg_lo:[1,0,0]"
               : "=v"(d) : "v"(a), "v"(b), "v"(c)); return d;
}
// d.lo = a.lo*b.hi + c.lo ; d.hi = -a.hi*b.lo + c.hi
__device__ __forceinline__ v2f pk_fma_swh(v2f a, v2f b, v2f c) {
    v2f d; asm("v_pk_fma_f32 %0, %1, %2, %3 op_sel:[0,1,0] op_sel_hi:[1,0,1] neg_hi:[1,0,0]"
               : "=v"(d) : "v"(a), "v"(b), "v"(c)); return d;
}
// z * (re + i*im), complex scalar in C2
__device__ __forceinline__ v2f cmulv(v2f z, C2 c) {
    v2f n = pk_mul((v2f){c.re, c.re}, z);
    return pk_fma_swl((v2f){c.im, c.im}, z, n);
}

// ---------------- cross-lane exchange ----------------
template<int CTRL>
__device__ __forceinline__ float dppf(float x) {
    int xi = __float_as_int(x);
    int r = __builtin_amdgcn_update_dpp(xi, xi, CTRL, 0xF, 0xF, false);
    return __int_as_float(r);
}
template<int M>
__device__ __forceinline__ float lxor(float x) {
    if constexpr (M == 1)      return dppf<0xB1>(x);   // quad_perm [1,0,3,2]
    else if constexpr (M == 2) return dppf<0x4E>(x);   // quad_perm [2,3,0,1]
    else                       return __int_as_float(
        __builtin_amdgcn_ds_swizzle(__float_as_int(x), 0x101F));  // lane^4
}

// ---------------- gates ----------------
// fused SU(2) gate G = Rot * RY: columns (a,b); G = [[a,-conj(b)],[b,conj(a)]]
__device__ __forceinline__ void load_G2(const float* __restrict__ c_lds, int g,
                                        float cc, float ss,
                                        float& ar, float& ai, float& br, float& bi) {
    const float4 c0 = *(const float4*)(c_lds + 4 * g);  // aR.re aR.im bR.re bR.im
    ar = fmaf(c0.x, cc, -c0.z * ss);
    ai = fmaf(c0.y, cc,  c0.w * ss);
    br = fmaf(c0.z, cc,  c0.x * ss);
    bi = fmaf(c0.w, cc, -c0.y * ss);
}

// cross-lane SU(2): new = cS*z + cO*p, coefficients pre-sign-adjusted per lane
// (lo lane: cS=(ar,ai), cO=(-br,bi); hi lane: cS=(ar,-ai), cO=(br,bi))
template<int M>
__device__ __forceinline__ void su2_cross(v2f cSr, v2f cSi, v2f cOr, v2f cOi,
                                          v2f z[32]) {
#pragma unroll
    for (int t = 0; t < 32; t++) {
        v2f p;
        p.x = lxor<M>(z[t].x);
        p.y = lxor<M>(z[t].y);
        v2f n = pk_mul(cSr, z[t]);
        n = pk_fma_swl(cSi, z[t], n);
        n = pk_fma   (cOr, p, n);
        n = pk_fma_swl(cOi, p, n);
        z[t] = n;
    }
}

// in-lane SU(2) on reg-index bit ST
template<int ST>
__device__ __forceinline__ void su2_inlane(v2f arr, v2f aii, v2f brr, v2f bii,
                                           v2f z[32]) {
#pragma unroll
    for (int t = 0; t < 32; t++) {
        if ((t & ST) == 0) {
            const int u = t + ST;
            v2f x = z[t], y = z[u];
            v2f nx = pk_mul(arr, x);
            nx = pk_fma_swl(aii, x, nx);
            nx = pk_fma_nn (brr, y, nx);
            nx = pk_fma_swl(bii, y, nx);
            v2f ny = pk_mul(brr, x);
            ny = pk_fma_swl(bii, x, ny);
            ny = pk_fma   (arr, y, ny);
            ny = pk_fma_swh(aii, y, ny);
            z[t] = nx; z[u] = ny;
        }
    }
}

// final RY: cross (cO pre-signed per lane)
template<int M>
__device__ __forceinline__ void ry_cross(v2f cc, v2f cO, v2f z[32]) {
#pragma unroll
    for (int t = 0; t < 32; t++) {
        v2f p;
        p.x = lxor<M>(z[t].x);
        p.y = lxor<M>(z[t].y);
        z[t] = pk_fma(cO, p, pk_mul(cc, z[t]));
    }
}
template<int ST>
__device__ __forceinline__ void ry_inlane(v2f cc, v2f ss, v2f z[32]) {
#pragma unroll
    for (int t = 0; t < 32; t++) {
        if ((t & ST) == 0) {
            const int u = t + ST;
            v2f x = z[t], y = z[u];
            z[t] = pk_fma_nn(ss, y, pk_mul(cc, x));   // c*x - s*y
            z[u] = pk_fma   (cc, y, pk_mul(ss, x));   // s*x + c*y
        }
    }
}

// CZ t-part (5-bit): parity of adjacent-bit ANDs (t4&t3)+(t3&t2)+(t2&t1)+(t1&t0)
__host__ __device__ constexpr bool czt5(int t) {
    return ((((t >> 4) & (t >> 3)) ^ ((t >> 3) & (t >> 2)) ^
             ((t >> 2) & (t >> 1)) ^ ((t >> 1) & t)) & 1) != 0;
}

__global__ __launch_bounds__(128, 2) void qdqn_kernel(
    const float* __restrict__ x,
    const float* __restrict__ ew1, const float* __restrict__ eb1,
    const float* __restrict__ ew2, const float* __restrict__ eb2,
    const float* __restrict__ qw,
    const float* __restrict__ dw1, const float* __restrict__ db1,
    const float* __restrict__ dw2, const float* __restrict__ db2,
    float* __restrict__ out, int B, int NL) {
    __shared__ __align__(16) float c_lds[32 * 4];
    __shared__ __align__(16) float hx[2][8][8];     // h / h2 exchange
    __shared__ __align__(16) float csx[2][8][16];   // (c,s) exchange

    const int tid = threadIdx.x;
    const int n_gates = NL * 8;

    // ---- Rot SU(2) coeffs once per block: a = e^{-iA}c, b = e^{-iB}s ----
    if (tid < n_gates) {
        const int g = tid;
        float phi = qw[3 * g + 0], th = qw[3 * g + 1], om = qw[3 * g + 2];
        float c = __cosf(0.5f * th), s = __sinf(0.5f * th);
        float A = 0.5f * (phi + om), Bb = 0.5f * (phi - om);
        float* o = c_lds + 4 * g;
        o[0] =  __cosf(A) * c;  o[1] = -__sinf(A) * c;
        o[2] =  __cosf(Bb) * s; o[3] = -__sinf(Bb) * s;
    }
    __syncthreads();

    const int wave = tid >> 6;
    const int lane = tid & 63;
    const int grp = lane >> 3;      // sample subgroup within wave (0..7)
    const int g = lane & 7;         // lane within sample = amp bits 7..5
    int s = blockIdx.x * 16 + wave * 8 + grp;
    if (s >= B) s = B - 1;

    // ---------------- encoder MLP, split across the 8 lanes ----------------
    float cq[8], sq[8];
    {
        float xv[16];
        const float4* xp = (const float4*)(x + s * 16);
#pragma unroll
        for (int i = 0; i < 4; i++) {
            float4 v = xp[i];
            xv[4*i] = v.x; xv[4*i+1] = v.y; xv[4*i+2] = v.z; xv[4*i+3] = v.w;
        }
        // lane computes row g of W1
        float a = eb1[g];
#pragma unroll
        for (int i = 0; i < 16; i++) a = fmaf(ew1[g * 16 + i], xv[i], a);
        hx[wave][grp][g] = fmaxf(a, 0.0f);
        __builtin_amdgcn_wave_barrier();
        float4 h01 = *(const float4*)&hx[wave][grp][0];
        float4 h23 = *(const float4*)&hx[wave][grp][4];
        // lane computes qubit g of layer 2 + transcendentals
        float b = eb2[g];
        b = fmaf(ew2[g*8+0], h01.x, b); b = fmaf(ew2[g*8+1], h01.y, b);
        b = fmaf(ew2[g*8+2], h01.z, b); b = fmaf(ew2[g*8+3], h01.w, b);
        b = fmaf(ew2[g*8+4], h23.x, b); b = fmaf(ew2[g*8+5], h23.y, b);
        b = fmaf(ew2[g*8+6], h23.z, b); b = fmaf(ew2[g*8+7], h23.w, b);
        float e = 1.0f - __fdividef(2.0f, __expf(2.0f * b) + 1.0f);  // tanh
        float ang = e * (0.5f * PI_F);
        float2* cso = (float2*)&csx[wave][grp][2 * g];
        *cso = make_float2(__cosf(ang), __sinf(ang));
        __builtin_amdgcn_wave_barrier();
#pragma unroll
        for (int k = 0; k < 4; k++) {
            float4 v = *(const float4*)&csx[wave][grp][4 * k];
            cq[2*k] = v.x; sq[2*k] = v.y; cq[2*k+1] = v.z; sq[2*k+1] = v.w;
        }
    }

    // ---- per-lane sign masks for cross wires q=0..2 (lane bit 2-q) ----
    int hiM[3], loM[3];
#pragma unroll
    for (int q = 0; q < 3; q++) {
        int hi = (g >> (2 - q)) & 1;
        hiM[q] = hi << 31;                 // flips ai when hi lane
        loM[q] = hiM[q] ^ 0x80000000;      // flips br when lo lane
    }

    // ---- CZ lane scalars: amp=(G<<5)|t; pairs (G2&G1)+(G1&G0)+(G0&t4)+t-part
    const int g0b = g & 1, g1b = (g >> 1) & 1, g2b = (g >> 2) & 1;
    const float mLo = ((g2b & g1b) ^ (g1b & g0b)) ? -1.0f : 1.0f;  // t < 16
    const float mHi = g0b ? -mLo : mLo;                            // t >= 16
    const v2f mLo2 = (v2f){mLo, mLo}, mHi2 = (v2f){mHi, mHi};

    // ---------------- layer 0: product state, CZ folded --------------------
    v2f z[32];
    {
        C2 P; P.re = 1.0f; P.im = 0.0f;
        C2 A[5], Bc[5];
#pragma unroll
        for (int q = 0; q < 8; q++) {
            float ar, ai, br, bi;
            load_G2(c_lds, q, cq[q], sq[q], ar, ai, br, bi);
            if (q < 3) {
                const bool hi = (g >> (2 - q)) & 1;
                C2 f; f.re = hi ? br : ar; f.im = hi ? bi : ai;  // column 0
                P = cmul(P, f);
            } else {
                A[q-3].re = ar;  A[q-3].im = ai;
                Bc[q-3].re = br; Bc[q-3].im = bi;
            }
        }
        z[0] = (v2f){P.re, P.im};
#pragma unroll
        for (int w = 0; w < 5; w++) {
            const int n = 1 << w;
#pragma unroll
            for (int i = n - 1; i >= 0; i--) {
                v2f v = z[i];
                z[2*i+1] = cmulv(v, Bc[w]);
                z[2*i]   = cmulv(v, A[w]);
            }
        }
#pragma unroll
        for (int t = 0; t < 32; t++) {
            v2f m = (t < 16) ? mLo2 : mHi2;
            z[t] = czt5(t) ? pk_mul_neg(m, z[t]) : pk_mul(m, z[t]);
        }
    }

    // ---------------- layers 1..NL-1 ---------------------------------------
    for (int l = 1; l < NL; l++) {
        const int gb = l * 8;
        float ar, ai, br, bi;
        load_G2(c_lds, gb+0, cq[0], sq[0], ar, ai, br, bi);
        su2_cross<4>((v2f){ar,ar}, (v2f){fxor(ai,hiM[0]),fxor(ai,hiM[0])},
                     (v2f){fxor(br,loM[0]),fxor(br,loM[0])}, (v2f){bi,bi}, z);
        load_G2(c_lds, gb+1, cq[1], sq[1], ar, ai, br, bi);
        su2_cross<2>((v2f){ar,ar}, (v2f){fxor(ai,hiM[1]),fxor(ai,hiM[1])},
                     (v2f){fxor(br,loM[1]),fxor(br,loM[1])}, (v2f){bi,bi}, z);
        load_G2(c_lds, gb+2, cq[2], sq[2], ar, ai, br, bi);
        su2_cross<1>((v2f){ar,ar}, (v2f){fxor(ai,hiM[2]),fxor(ai,hiM[2])},
                     (v2f){fxor(br,loM[2]),fxor(br,loM[2])}, (v2f){bi,bi}, z);
        load_G2(c_lds, gb+3, cq[3], sq[3], ar, ai, br, bi);
        su2_inlane<16>((v2f){ar,ar}, (v2f){ai,ai}, (v2f){br,br}, (v2f){bi,bi}, z);
        load_G2(c_lds, gb+4, cq[4], sq[4], ar, ai, br, bi);
        su2_inlane<8>((v2f){ar,ar}, (v2f){ai,ai}, (v2f){br,br}, (v2f){bi,bi}, z);
        load_G2(c_lds, gb+5, cq[5], sq[5], ar, ai, br, bi);
        su2_inlane<4>((v2f){ar,ar}, (v2f){ai,ai}, (v2f){br,br}, (v2f){bi,bi}, z);
        load_G2(c_lds, gb+6, cq[6], sq[6], ar, ai, br, bi);
        su2_inlane<2>((v2f){ar,ar}, (v2f){ai,ai}, (v2f){br,br}, (v2f){bi,bi}, z);
        load_G2(c_lds, gb+7, cq[7], sq[7], ar, ai, br, bi);
        su2_inlane<1>((v2f){ar,ar}, (v2f){ai,ai}, (v2f){br,br}, (v2f){bi,bi}, z);
        // CZ diagonal
#pragma unroll
        for (int t = 0; t < 32; t++) {
            v2f m = (t < 16) ? mLo2 : mHi2;
            z[t] = czt5(t) ? pk_mul_neg(m, z[t]) : pk_mul(m, z[t]);
        }
    }

    // ---------------- final RY layer ---------------------------------------
    {
        v2f cc, cO, ss;
        cc=(v2f){cq[0],cq[0]}; cO=(v2f){fxor(sq[0],loM[0]),fxor(sq[0],loM[0])};
        ry_cross<4>(cc, cO, z);
        cc=(v2f){cq[1],cq[1]}; cO=(v2f){fxor(sq[1],loM[1]),fxor(sq[1],loM[1])};
        ry_cross<2>(cc, cO, z);
        cc=(v2f){cq[2],cq[2]}; cO=(v2f){fxor(sq[2],loM[2]),fxor(sq[2],loM[2])};
        ry_cross<1>(cc, cO, z);
        cc=(v2f){cq[3],cq[3]}; ss=(v2f){sq[3],sq[3]}; ry_inlane<16>(cc, ss, z);
        cc=(v2f){cq[4],cq[4]}; ss=(v2f){sq[4],sq[4]}; ry_inlane<8>(cc, ss, z);
        cc=(v2f){cq[5],cq[5]}; ss=(v2f){sq[5],sq[5]}; ry_inlane<4>(cc, ss, z);
        cc=(v2f){cq[6],cq[6]}; ss=(v2f){sq[6],sq[6]}; ry_inlane<2>(cc, ss, z);
        cc=(v2f){cq[7],cq[7]}; ss=(v2f){sq[7],sq[7]}; ry_inlane<1>(cc, ss, z);
    }

    // ---------------- probs -> <Z_w> ----------------
    float p[32];
#pragma unroll
    for (int t = 0; t < 32; t++) p[t] = fmaf(z[t].x, z[t].x, z[t].y * z[t].y);

    float s16[16], zW[8];
    {
        float d = 0.0f;
#pragma unroll
        for (int i = 0; i < 16; i++) {
            s16[i] = p[2*i] + p[2*i+1];
            d += p[2*i] - p[2*i+1];
        }
        zW[7] = d;
        float s8[8]; d = 0.0f;
#pragma unroll
        for (int i = 0; i < 8; i++) {
            s8[i] = s16[2*i] + s16[2*i+1];
            d += s16[2*i] - s16[2*i+1];
        }
        zW[6] = d;
        float s4[4]; d = 0.0f;
#pragma unroll
        for (int i = 0; i < 4; i++) {
            s4[i] = s8[2*i] + s8[2*i+1];
            d += s8[2*i] - s8[2*i+1];
        }
        zW[5] = d;
        float s2a = s4[0] + s4[1], s2b = s4[2] + s4[3];
        zW[4] = (s4[0] - s4[1]) + (s4[2] - s4[3]);
        float sumP = s2a + s2b;
        zW[3] = s2a - s2b;
        zW[0] = g2b ? -sumP : sumP;
        zW[1] = g1b ? -sumP : sumP;
        zW[2] = g0b ? -sumP : sumP;
    }
    // all-reduce across the 8 lanes of the sample
#pragma unroll
    for (int w = 0; w < 8; w++) zW[w] += lxor<1>(zW[w]);
#pragma unroll
    for (int w = 0; w < 8; w++) zW[w] += lxor<2>(zW[w]);
#pragma unroll
    for (int w = 0; w < 8; w++) zW[w] += lxor<4>(zW[w]);

    // ---------------- decoder MLP, split across lanes ----------------------
    {
        float a = db1[g];
#pragma unroll
        for (int w = 0; w < 8; w++) a = fmaf(dw1[g * 8 + w], zW[w], a);
        hx[wave][grp][g] = fmaxf(a, 0.0f);
        __builtin_amdgcn_wave_barrier();
        float4 h01 = *(const float4*)&hx[wave][grp][0];
        float4 h23 = *(const float4*)&hx[wave][grp][4];
        const int o = g & 3;   // lanes g and g+4 compute identical output o
        float acc = db2[o];
        acc = fmaf(dw2[o*8+0], h01.x, acc); acc = fmaf(dw2[o*8+1], h01.y, acc);
        acc = fmaf(dw2[o*8+2], h01.z, acc); acc = fmaf(dw2[o*8+3], h01.w, acc);
        acc = fmaf(dw2[o*8+4], h23.x, acc); acc = fmaf(dw2[o*8+5], h23.y, acc);
        acc = fmaf(dw2[o*8+6], h23.z, acc); acc = fmaf(dw2[o*8+7], h23.w, acc);
        out[s * 4 + o] = acc;
    }
}

extern "C" void kernel_launch(void* const* d_in, const int* in_sizes, int n_in,
                              void* d_out, int out_size, void* d_ws, size_t ws_size,
                              hipStream_t stream) {
    const float* x   = (const float*)d_in[0];
    const float* ew1 = (const float*)d_in[1];
    const float* eb1 = (const float*)d_in[2];
    const float* ew2 = (const float*)d_in[3];
    const float* eb2 = (const float*)d_in[4];
    const float* qw  = (const float*)d_in[5];
    const float* dw1 = (const float*)d_in[6];
    const float* db1 = (const float*)d_in[7];
    const float* dw2 = (const float*)d_in[8];
    const float* db2 = (const float*)d_in[9];
    float* out = (float*)d_out;

    int B = in_sizes[0] / 16;        // 32768
    int n_gates = in_sizes[5] / 3;   // 32
    int NL = n_gates / 8;            // 4

    // 16 samples per 128-thread block (2 waves x 8 samples/wave)
    int blocks = (B + 15) / 16;
    qdqn_kernel<<<blocks, 128, 0, stream>>>(x, ew1, eb1, ew2, eb2, qw,
                                            dw1, db1, dw2, db2, out, B, NL);
}

// Round 7
// 117.201 us; speedup vs baseline: 1.0586x; 1.0220x over previous
//
#include <hip/hip_runtime.h>
#include <math.h>

// ---------------------------------------------------------------------------
// HybridQuantumDQN: encoder MLP -> 8-qubit statevector sim -> decoder MLP.
// Round 7: R6 structure (8 samples/wave64; 8 lanes/sample; 32 complex amps
// per lane as v2f; packed fp32 v_pk_fma_f32 for all state math), with the
// sample's 8 lanes remapped to lane bits {0,1,3} so ALL cross-wire exchanges
// are DPP (xor1/xor2 = quad_perm, xor8 = row_ror:8) - zero ds_swizzle in the
// gate loops (R6's wire-0 xor4 ds_swizzles were the suspected lgkm stall).
// Cross-wire updates are chunked: gather 8 regs' partners via DPP, then the
// 32 pk ops - separates DPP reads from producer writes (hazard nops) and
// caps live partner regs. amp = (G<<5)|t: G = lane bits {3,1,0} (amp bits
// 7..5), t = reg idx (amp bits 4..0). Wires 0..2 cross (xor8/2/1), 3..7
// in-lane. Encoder/decoder/transcendentals split across the 8 lanes via tiny
// wave-local LDS exchanges. Layer 0 = product state. CZ = closed-form +-1.
// ---------------------------------------------------------------------------

#define PI_F 3.14159265358979323846f

typedef float v2f __attribute__((ext_vector_type(2)));

struct C2 { float re, im; };
__device__ __forceinline__ C2 cmul(C2 a, C2 b) {
    C2 r;
    r.re = fmaf(a.re, b.re, -a.im * b.im);
    r.im = fmaf(a.re, b.im,  a.im * b.re);
    return r;
}
__device__ __forceinline__ float fxor(float x, int m) {
    return __int_as_float(__float_as_int(x) ^ m);
}

// ---------------- packed fp32 primitives (VOP3P) ----------------
__device__ __forceinline__ v2f pk_mul(v2f a, v2f b) {
    v2f d; asm("v_pk_mul_f32 %0, %1, %2" : "=v"(d) : "v"(a), "v"(b)); return d;
}
__device__ __forceinline__ v2f pk_mul_neg(v2f a, v2f b) {
    v2f d; asm("v_pk_mul_f32 %0, %1, %2 neg_lo:[1,0] neg_hi:[1,0]"
               : "=v"(d) : "v"(a), "v"(b)); return d;
}
__device__ __forceinline__ v2f pk_fma(v2f a, v2f b, v2f c) {
    v2f d; asm("v_pk_fma_f32 %0, %1, %2, %3" : "=v"(d) : "v"(a), "v"(b), "v"(c)); return d;
}
// d = -(a*b) + c
__device__ __forceinline__ v2f pk_fma_nn(v2f a, v2f b, v2f c) {
    v2f d; asm("v_pk_fma_f32 %0, %1, %2, %3 neg_lo:[1,0,0] neg_hi:[1,0,0]"
               : "=v"(d) : "v"(a), "v"(b), "v"(c)); return d;
}
// d.lo = -a.lo*b.hi + c.lo ; d.hi = a.hi*b.lo + c.hi   (complex cross term)
__device__ __forceinline__ v2f pk_fma_swl(v2f a, v2f b, v2f c) {
    v2f d; asm("v_pk_fma_f32 %0, %1, %2, %3 op_sel:[0,1,0] op_sel_hi:[1,0,1] neg_lo:[1,0,0]"
               : "=v"(d) : "v"(a), "v"(b), "v"(c)); return d;
}
// d.lo = a.lo*b.hi + c.lo ; d.hi = -a.hi*b.lo + c.hi
__device__ __forceinline__ v2f pk_fma_swh(v2f a, v2f b, v2f c) {
    v2f d; asm("v_pk_fma_f32 %0, %1, %2, %3 op_sel:[0,1,0] op_sel_hi:[1,0,1] neg_hi:[1,0,0]"
               : "=v"(d) : "v"(a), "v"(b), "v"(c)); return d;
}
// z * (re + i*im), complex scalar in C2
__device__ __forceinline__ v2f cmulv(v2f z, C2 c) {
    v2f n = pk_mul((v2f){c.re, c.re}, z);
    return pk_fma_swl((v2f){c.im, c.im}, z, n);
}

// ---------------- cross-lane exchange (all DPP) ----------------
template<int CTRL>
__device__ __forceinline__ float dppf(float x) {
    int xi = __float_as_int(x);
    int r = __builtin_amdgcn_update_dpp(xi, xi, CTRL, 0xF, 0xF, false);
    return __int_as_float(r);
}
template<int M>
__device__ __forceinline__ float lxor(float x) {
    if constexpr (M == 1)      return dppf<0xB1>(x);   // quad_perm [1,0,3,2]
    else if constexpr (M == 2) return dppf<0x4E>(x);   // quad_perm [2,3,0,1]
    else                       return dppf<0x128>(x);  // row_ror:8 == lane^8 in row16
}

// ---------------- gates ----------------
// fused SU(2) gate G = Rot * RY: columns (a,b); G = [[a,-conj(b)],[b,conj(a)]]
__device__ __forceinline__ void load_G2(const float* __restrict__ c_lds, int g,
                                        float cc, float ss,
                                        float& ar, float& ai, float& br, float& bi) {
    const float4 c0 = *(const float4*)(c_lds + 4 * g);  // aR.re aR.im bR.re bR.im
    ar = fmaf(c0.x, cc, -c0.z * ss);
    ai = fmaf(c0.y, cc,  c0.w * ss);
    br = fmaf(c0.z, cc,  c0.x * ss);
    bi = fmaf(c0.w, cc, -c0.y * ss);
}

// cross-lane SU(2): new = cS*z + cO*p, coefficients pre-sign-adjusted per lane
// (lo lane: cS=(ar,ai), cO=(-br,bi); hi lane: cS=(ar,-ai), cO=(br,bi))
// Chunked: gather 8 partners (16 DPP) then 32 pk -> hazard-free, low reg peak.
template<int M>
__device__ __forceinline__ void su2_cross(v2f cSr, v2f cSi, v2f cOr, v2f cOi,
                                          v2f z[32]) {
#pragma unroll
    for (int c = 0; c < 4; c++) {
        v2f p[8];
#pragma unroll
        for (int k = 0; k < 8; k++) {
            p[k].x = lxor<M>(z[c * 8 + k].x);
            p[k].y = lxor<M>(z[c * 8 + k].y);
        }
#pragma unroll
        for (int k = 0; k < 8; k++) {
            const int t = c * 8 + k;
            v2f n = pk_mul(cSr, z[t]);
            n = pk_fma_swl(cSi, z[t], n);
            n = pk_fma   (cOr, p[k], n);
            n = pk_fma_swl(cOi, p[k], n);
            z[t] = n;
        }
    }
}

// in-lane SU(2) on reg-index bit ST
template<int ST>
__device__ __forceinline__ void su2_inlane(v2f arr, v2f aii, v2f brr, v2f bii,
                                           v2f z[32]) {
#pragma unroll
    for (int t = 0; t < 32; t++) {
        if ((t & ST) == 0) {
            const int u = t + ST;
            v2f x = z[t], y = z[u];
            v2f nx = pk_mul(arr, x);
            nx = pk_fma_swl(aii, x, nx);
            nx = pk_fma_nn (brr, y, nx);
            nx = pk_fma_swl(bii, y, nx);
            v2f ny = pk_mul(brr, x);
            ny = pk_fma_swl(bii, x, ny);
            ny = pk_fma   (arr, y, ny);
            ny = pk_fma_swh(aii, y, ny);
            z[t] = nx; z[u] = ny;
        }
    }
}

// final RY: cross (cO pre-signed per lane), chunked like su2_cross
template<int M>
__device__ __forceinline__ void ry_cross(v2f cc, v2f cO, v2f z[32]) {
#pragma unroll
    for (int c = 0; c < 4; c++) {
        v2f p[8];
#pragma unroll
        for (int k = 0; k < 8; k++) {
            p[k].x = lxor<M>(z[c * 8 + k].x);
            p[k].y = lxor<M>(z[c * 8 + k].y);
        }
#pragma unroll
        for (int k = 0; k < 8; k++) {
            const int t = c * 8 + k;
            z[t] = pk_fma(cO, p[k], pk_mul(cc, z[t]));
        }
    }
}
template<int ST>
__device__ __forceinline__ void ry_inlane(v2f cc, v2f ss, v2f z[32]) {
#pragma unroll
    for (int t = 0; t < 32; t++) {
        if ((t & ST) == 0) {
            const int u = t + ST;
            v2f x = z[t], y = z[u];
            z[t] = pk_fma_nn(ss, y, pk_mul(cc, x));   // c*x - s*y
            z[u] = pk_fma   (cc, y, pk_mul(ss, x));   // s*x + c*y
        }
    }
}

// CZ t-part (5-bit): parity of adjacent-bit ANDs
__host__ __device__ constexpr bool czt5(int t) {
    return ((((t >> 4) & (t >> 3)) ^ ((t >> 3) & (t >> 2)) ^
             ((t >> 2) & (t >> 1)) ^ ((t >> 1) & t)) & 1) != 0;
}

__global__ __launch_bounds__(128, 2) void qdqn_kernel(
    const float* __restrict__ x,
    const float* __restrict__ ew1, const float* __restrict__ eb1,
    const float* __restrict__ ew2, const float* __restrict__ eb2,
    const float* __restrict__ qw,
    const float* __restrict__ dw1, const float* __restrict__ db1,
    const float* __restrict__ dw2, const float* __restrict__ db2,
    float* __restrict__ out, int B, int NL) {
    __shared__ __align__(16) float c_lds[32 * 4];
    __shared__ __align__(16) float hx[2][8][8];     // h / h2 exchange
    __shared__ __align__(16) float csx[2][8][16];   // (c,s) exchange

    const int tid = threadIdx.x;
    const int wave = tid >> 6;
    const int lane = tid & 63;
    // sample lane bits {0,1,3}; sample id bits {2,4,5} -> all-DPP cross wires
    const int g = (lane & 3) | ((lane >> 1) & 4);          // amp bits 7..5
    const int grp = ((lane >> 2) & 1) | ((lane >> 3) & 6); // sample in wave
    int s = blockIdx.x * 16 + wave * 8 + grp;
    if (s >= B) s = B - 1;

    // ---- prefetch x early (overlaps coef computation + barrier) ----
    float xv[16];
    {
        const float4* xp = (const float4*)(x + s * 16);
#pragma unroll
        for (int i = 0; i < 4; i++) {
            float4 v = xp[i];
            xv[4*i] = v.x; xv[4*i+1] = v.y; xv[4*i+2] = v.z; xv[4*i+3] = v.w;
        }
    }

    // ---- Rot SU(2) coeffs once per block: a = e^{-iA}c, b = e^{-iB}s ----
    const int n_gates = NL * 8;
    if (tid < n_gates) {
        const int gg = tid;
        float phi = qw[3 * gg + 0], th = qw[3 * gg + 1], om = qw[3 * gg + 2];
        float c = __cosf(0.5f * th), sv = __sinf(0.5f * th);
        float A = 0.5f * (phi + om), Bb = 0.5f * (phi - om);
        float* o = c_lds + 4 * gg;
        o[0] =  __cosf(A) * c;   o[1] = -__sinf(A) * c;
        o[2] =  __cosf(Bb) * sv; o[3] = -__sinf(Bb) * sv;
    }
    __syncthreads();

    // ---------------- encoder MLP, split across the 8 lanes ----------------
    float cq[8], sq[8];
    {
        // lane computes row g of W1
        float a = eb1[g];
#pragma unroll
        for (int i = 0; i < 16; i++) a = fmaf(ew1[g * 16 + i], xv[i], a);
        hx[wave][grp][g] = fmaxf(a, 0.0f);
        __builtin_amdgcn_wave_barrier();
        float4 h01 = *(const float4*)&hx[wave][grp][0];
        float4 h23 = *(const float4*)&hx[wave][grp][4];
        // lane computes qubit g of layer 2 + transcendentals
        float b = eb2[g];
        b = fmaf(ew2[g*8+0], h01.x, b); b = fmaf(ew2[g*8+1], h01.y, b);
        b = fmaf(ew2[g*8+2], h01.z, b); b = fmaf(ew2[g*8+3], h01.w, b);
        b = fmaf(ew2[g*8+4], h23.x, b); b = fmaf(ew2[g*8+5], h23.y, b);
        b = fmaf(ew2[g*8+6], h23.z, b); b = fmaf(ew2[g*8+7], h23.w, b);
        float e = 1.0f - __fdividef(2.0f, __expf(2.0f * b) + 1.0f);  // tanh
        float ang = e * (0.5f * PI_F);
        float2* cso = (float2*)&csx[wave][grp][2 * g];
        *cso = make_float2(__cosf(ang), __sinf(ang));
        __builtin_amdgcn_wave_barrier();
#pragma unroll
        for (int k = 0; k < 4; k++) {
            float4 v = *(const float4*)&csx[wave][grp][4 * k];
            cq[2*k] = v.x; sq[2*k] = v.y; cq[2*k+1] = v.z; sq[2*k+1] = v.w;
        }
    }

    // ---- per-lane sign masks for cross wires q=0..2 (logical bit 2-q of g)
    int hiM[3], loM[3];
#pragma unroll
    for (int q = 0; q < 3; q++) {
        int hi = (g >> (2 - q)) & 1;
        hiM[q] = hi << 31;                 // flips ai when hi lane
        loM[q] = hiM[q] ^ 0x80000000;      // flips br when lo lane
    }

    // ---- CZ lane scalars: amp=(G<<5)|t; pairs (G2&G1)+(G1&G0)+(G0&t4)+t-part
    const int g0b = g & 1, g1b = (g >> 1) & 1, g2b = (g >> 2) & 1;
    const float mLo = ((g2b & g1b) ^ (g1b & g0b)) ? -1.0f : 1.0f;  // t < 16
    const float mHi = g0b ? -mLo : mLo;                            // t >= 16
    const v2f mLo2 = (v2f){mLo, mLo}, mHi2 = (v2f){mHi, mHi};

    // ---------------- layer 0: product state, CZ folded --------------------
    v2f z[32];
    {
        C2 P; P.re = 1.0f; P.im = 0.0f;
        C2 A[5], Bc[5];
#pragma unroll
        for (int q = 0; q < 8; q++) {
            float ar, ai, br, bi;
            load_G2(c_lds, q, cq[q], sq[q], ar, ai, br, bi);
            if (q < 3) {
                const bool hi = (g >> (2 - q)) & 1;
                C2 f; f.re = hi ? br : ar; f.im = hi ? bi : ai;  // column 0
                P = cmul(P, f);
            } else {
                A[q-3].re = ar;  A[q-3].im = ai;
                Bc[q-3].re = br; Bc[q-3].im = bi;
            }
        }
        z[0] = (v2f){P.re, P.im};
#pragma unroll
        for (int w = 0; w < 5; w++) {
            const int n = 1 << w;
#pragma unroll
            for (int i = n - 1; i >= 0; i--) {
                v2f v = z[i];
                z[2*i+1] = cmulv(v, Bc[w]);
                z[2*i]   = cmulv(v, A[w]);
            }
        }
#pragma unroll
        for (int t = 0; t < 32; t++) {
            v2f m = (t < 16) ? mLo2 : mHi2;
            z[t] = czt5(t) ? pk_mul_neg(m, z[t]) : pk_mul(m, z[t]);
        }
    }

    // ---------------- layers 1..NL-1 ---------------------------------------
    for (int l = 1; l < NL; l++) {
        const int gb = l * 8;
        float ar, ai, br, bi;
        load_G2(c_lds, gb+0, cq[0], sq[0], ar, ai, br, bi);
        su2_cross<8>((v2f){ar,ar}, (v2f){fxor(ai,hiM[0]),fxor(ai,hiM[0])},
                     (v2f){fxor(br,loM[0]),fxor(br,loM[0])}, (v2f){bi,bi}, z);
        load_G2(c_lds, gb+1, cq[1], sq[1], ar, ai, br, bi);
        su2_cross<2>((v2f){ar,ar}, (v2f){fxor(ai,hiM[1]),fxor(ai,hiM[1])},
                     (v2f){fxor(br,loM[1]),fxor(br,loM[1])}, (v2f){bi,bi}, z);
        load_G2(c_lds, gb+2, cq[2], sq[2], ar, ai, br, bi);
        su2_cross<1>((v2f){ar,ar}, (v2f){fxor(ai,hiM[2]),fxor(ai,hiM[2])},
                     (v2f){fxor(br,loM[2]),fxor(br,loM[2])}, (v2f){bi,bi}, z);
        load_G2(c_lds, gb+3, cq[3], sq[3], ar, ai, br, bi);
        su2_inlane<16>((v2f){ar,ar}, (v2f){ai,ai}, (v2f){br,br}, (v2f){bi,bi}, z);
        load_G2(c_lds, gb+4, cq[4], sq[4], ar, ai, br, bi);
        su2_inlane<8>((v2f){ar,ar}, (v2f){ai,ai}, (v2f){br,br}, (v2f){bi,bi}, z);
        load_G2(c_lds, gb+5, cq[5], sq[5], ar, ai, br, bi);
        su2_inlane<4>((v2f){ar,ar}, (v2f){ai,ai}, (v2f){br,br}, (v2f){bi,bi}, z);
        load_G2(c_lds, gb+6, cq[6], sq[6], ar, ai, br, bi);
        su2_inlane<2>((v2f){ar,ar}, (v2f){ai,ai}, (v2f){br,br}, (v2f){bi,bi}, z);
        load_G2(c_lds, gb+7, cq[7], sq[7], ar, ai, br, bi);
        su2_inlane<1>((v2f){ar,ar}, (v2f){ai,ai}, (v2f){br,br}, (v2f){bi,bi}, z);
        // CZ diagonal
#pragma unroll
        for (int t = 0; t < 32; t++) {
            v2f m = (t < 16) ? mLo2 : mHi2;
            z[t] = czt5(t) ? pk_mul_neg(m, z[t]) : pk_mul(m, z[t]);
        }
    }

    // ---------------- final RY layer ---------------------------------------
    {
        v2f cc, cO, ss;
        cc=(v2f){cq[0],cq[0]}; cO=(v2f){fxor(sq[0],loM[0]),fxor(sq[0],loM[0])};
        ry_cross<8>(cc, cO, z);
        cc=(v2f){cq[1],cq[1]}; cO=(v2f){fxor(sq[1],loM[1]),fxor(sq[1],loM[1])};
        ry_cross<2>(cc, cO, z);
        cc=(v2f){cq[2],cq[2]}; cO=(v2f){fxor(sq[2],loM[2]),fxor(sq[2],loM[2])};
        ry_cross<1>(cc, cO, z);
        cc=(v2f){cq[3],cq[3]}; ss=(v2f){sq[3],sq[3]}; ry_inlane<16>(cc, ss, z);
        cc=(v2f){cq[4],cq[4]}; ss=(v2f){sq[4],sq[4]}; ry_inlane<8>(cc, ss, z);
        cc=(v2f){cq[5],cq[5]}; ss=(v2f){sq[5],sq[5]}; ry_inlane<4>(cc, ss, z);
        cc=(v2f){cq[6],cq[6]}; ss=(v2f){sq[6],sq[6]}; ry_inlane<2>(cc, ss, z);
        cc=(v2f){cq[7],cq[7]}; ss=(v2f){sq[7],sq[7]}; ry_inlane<1>(cc, ss, z);
    }

    // ---------------- probs -> <Z_w> ----------------
    float p[32];
#pragma unroll
    for (int t = 0; t < 32; t++) p[t] = fmaf(z[t].x, z[t].x, z[t].y * z[t].y);

    float s16[16], zW[8];
    {
        float d = 0.0f;
#pragma unroll
        for (int i = 0; i < 16; i++) {
            s16[i] = p[2*i] + p[2*i+1];
            d += p[2*i] - p[2*i+1];
        }
        zW[7] = d;
        float s8[8]; d = 0.0f;
#pragma unroll
        for (int i = 0; i < 8; i++) {
            s8[i] = s16[2*i] + s16[2*i+1];
            d += s16[2*i] - s16[2*i+1];
        }
        zW[6] = d;
        float s4[4]; d = 0.0f;
#pragma unroll
        for (int i = 0; i < 4; i++) {
            s4[i] = s8[2*i] + s8[2*i+1];
            d += s8[2*i] - s8[2*i+1];
        }
        zW[5] = d;
        float s2a = s4[0] + s4[1], s2b = s4[2] + s4[3];
        zW[4] = (s4[0] - s4[1]) + (s4[2] - s4[3]);
        float sumP = s2a + s2b;
        zW[3] = s2a - s2b;
        zW[0] = g2b ? -sumP : sumP;
        zW[1] = g1b ? -sumP : sumP;
        zW[2] = g0b ? -sumP : sumP;
    }
    // all-reduce across the 8 lanes of the sample (bits 0,1,3 -> all DPP)
#pragma unroll
    for (int w = 0; w < 8; w++) zW[w] += lxor<1>(zW[w]);
#pragma unroll
    for (int w = 0; w < 8; w++) zW[w] += lxor<2>(zW[w]);
#pragma unroll
    for (int w = 0; w < 8; w++) zW[w] += lxor<8>(zW[w]);

    // ---------------- decoder MLP, split across lanes ----------------------
    {
        float a = db1[g];
#pragma unroll
        for (int w = 0; w < 8; w++) a = fmaf(dw1[g * 8 + w], zW[w], a);
        hx[wave][grp][g] = fmaxf(a, 0.0f);
        __builtin_amdgcn_wave_barrier();
        float4 h01 = *(const float4*)&hx[wave][grp][0];
        float4 h23 = *(const float4*)&hx[wave][grp][4];
        const int o = g & 3;   // lanes g and g+4 compute identical output o
        float acc = db2[o];
        acc = fmaf(dw2[o*8+0], h01.x, acc); acc = fmaf(dw2[o*8+1], h01.y, acc);
        acc = fmaf(dw2[o*8+2], h01.z, acc); acc = fmaf(dw2[o*8+3], h01.w, acc);
        acc = fmaf(dw2[o*8+4], h23.x, acc); acc = fmaf(dw2[o*8+5], h23.y, acc);
        acc = fmaf(dw2[o*8+6], h23.z, acc); acc = fmaf(dw2[o*8+7], h23.w, acc);
        out[s * 4 + o] = acc;
    }
}

extern "C" void kernel_launch(void* const* d_in, const int* in_sizes, int n_in,
                              void* d_out, int out_size, void* d_ws, size_t ws_size,
                              hipStream_t stream) {
    const float* x   = (const float*)d_in[0];
    const float* ew1 = (const float*)d_in[1];
    const float* eb1 = (const float*)d_in[2];
    const float* ew2 = (const float*)d_in[3];
    const float* eb2 = (const float*)d_in[4];
    const float* qw  = (const float*)d_in[5];
    const float* dw1 = (const float*)d_in[6];
    const float* db1 = (const float*)d_in[7];
    const float* dw2 = (const float*)d_in[8];
    const float* db2 = (const float*)d_in[9];
    float* out = (float*)d_out;

    int B = in_sizes[0] / 16;        // 32768
    int n_gates = in_sizes[5] / 3;   // 32
    int NL = n_gates / 8;            // 4

    // 16 samples per 128-thread block (2 waves x 8 samples/wave)
    int blocks = (B + 15) / 16;
    qdqn_kernel<<<blocks, 128, 0, stream>>>(x, ew1, eb1, ew2, eb2, qw,
                                            dw1, db1, dw2, db2, out, B, NL);
}